// Round 6
// baseline (365.660 us; speedup 1.0000x reference)
//
#include <hip/hip_runtime.h>
#include <hip/hip_bf16.h>

// CrossAttention: B=4, C=256, N=4096, OUT=256, temp=16.
// v14: INSTRUMENTATION ROUND. Identical to v12 (best: 186.98us) except
//      qkv_proj's body runs PROJ_REP=10 times (idempotent re-writes,
//      asm memory clobber between reps defeats CSE/DSE). Purpose: proj has
//      never appeared in the duration-sorted top-5 (flash's 10x99us fills
//      it); two proj theories failed unverified. The 10x dispatch surfaces
//      proj's counters: dur = cold + 9*warm; total-187 = 9*warm.
//      Decision rules: low-BW/FETCH~50MB window -> cold-HBM-bound (wide-
//      strip restructure next); long+high-VALU/low-occ -> warm fix per
//      counter; still hidden -> proj<=35us -> gaps -> fusion next.
// flash_attn/wcvt byte-identical to v12 (flash 99.6us control).
// Workspace: qg 8.4MB + kt 8.4MB + vt 8.4MB + wb 384KB.

typedef __attribute__((ext_vector_type(8))) short bf16x8;
typedef __attribute__((ext_vector_type(4))) float f32x4;
typedef __attribute__((ext_vector_type(4))) short short4t;

constexpr int B_ = 4;
constexpr int C_ = 256;
constexpr int N_ = 4096;
constexpr int O_ = 256;
constexpr float INV_TEMP = 1.0f / 16.0f;
constexpr int NIT = 64;   // 64-key blocks (all 4096 keys, SPLIT=1)
constexpr int PROJ_REP = 10;  // instrumentation: x10 proj body

__device__ __forceinline__ short f2bf(float f) {
  union { float f; unsigned u; } v; v.f = f;
  unsigned r = v.u + 0x7fffu + ((v.u >> 16) & 1u);   // RNE
  return (short)(r >> 16);
}

// ---------------------------------------------------------------------------
__global__ void wcvt(const float* __restrict__ Wq, const float* __restrict__ Wk,
                     const float* __restrict__ Wv, short* __restrict__ wb) {
  int i = blockIdx.x * 256 + threadIdx.x;        // 0..196607
  int mat = i >> 16, off = i & 65535;
  const float* W = (mat == 0) ? Wq : (mat == 1 ? Wk : Wv);
  wb[i] = f2bf(W[off]);
}

// ---------------------------------------------------------------------------
// Projections (v12 structure). Grid (64, B, 3). Block 256 (4 waves).
// z: 0=Q, 1=K, 2=V. Body repeated PROJ_REP times for instrumentation.
// ---------------------------------------------------------------------------
__global__ __launch_bounds__(256, 2) void qkv_proj(
    const float* __restrict__ x, const float* __restrict__ xx,
    const short* __restrict__ wb,
    short* __restrict__ qg, short* __restrict__ kt, short* __restrict__ vt) {
  const int n0  = blockIdx.x * 64;
  const int b   = blockIdx.y;
  const int mat = blockIdx.z;
  const float* src = (mat == 0) ? x : xx;
  const short* W   = wb + mat * 65536;
  const int tid = threadIdx.x;
  const int w = tid >> 6, lane = tid & 63;
  const int g = lane >> 4, c16 = lane & 15;

  __shared__ __align__(16) short xs[64][264];   // staged tile / out assembly

  short* dst = (mat == 0) ? qg + ((size_t)b * N_ + n0) * O_
             : (mat == 1) ? kt + (size_t)(b * 256 + (n0 >> 4)) * 4096
                          : vt + (size_t)(b * 64 + (n0 >> 6)) * 16384;

#pragma unroll 1
  for (int rep = 0; rep < PROJ_REP; ++rep) {
    {  // transpose staging, MLP-deep: all 64 strided loads, then write.
      const int n = tid & 63, cq = tid >> 6;
      const float* sp = src + (size_t)b * C_ * N_ + n0 + n;
      float xr[64];                              // stays in VGPRs (static idx)
#pragma unroll
      for (int rp = 0; rp < 16; ++rp)
#pragma unroll
        for (int j = 0; j < 4; ++j)
          xr[rp * 4 + j] = sp[(size_t)(rp * 16 + cq * 4 + j) * N_];
#pragma unroll
      for (int rp = 0; rp < 16; ++rp) {
        int c = rp * 16 + cq * 4;
        short4t s4;
#pragma unroll
        for (int j = 0; j < 4; ++j) s4[j] = f2bf(xr[rp * 4 + j]);
        *(short4t*)&xs[n][c] = s4;
      }
    }
    __syncthreads();

    f32x4 acc[4][4];
#pragma unroll
    for (int i = 0; i < 4; ++i)
#pragma unroll
      for (int j = 0; j < 4; ++j) acc[i][j] = (f32x4){0.f, 0.f, 0.f, 0.f};

#pragma unroll
    for (int ko = 0; ko < 8; ++ko) {
      bf16x8 wfr[4], xfr[4];
#pragma unroll
      for (int ot = 0; ot < 4; ++ot)
        wfr[ot] = *(const bf16x8*)&W[(w * 64 + ot * 16 + c16) * C_ + ko * 32 + g * 8];
#pragma unroll
      for (int nt = 0; nt < 4; ++nt)
        xfr[nt] = *(const bf16x8*)&xs[nt * 16 + c16][ko * 32 + g * 8];
      if (mat < 2) {
#pragma unroll
        for (int ot = 0; ot < 4; ++ot)
#pragma unroll
          for (int nt = 0; nt < 4; ++nt)
            acc[ot][nt] = __builtin_amdgcn_mfma_f32_16x16x32_bf16(
                wfr[ot], xfr[nt], acc[ot][nt], 0, 0, 0);
      } else {  // V: swapped operands -> D rows = m, cols = o
#pragma unroll
        for (int mt = 0; mt < 4; ++mt)
#pragma unroll
          for (int ot = 0; ot < 4; ++ot)
            acc[mt][ot] = __builtin_amdgcn_mfma_f32_16x16x32_bf16(
                xfr[mt], wfr[ot], acc[mt][ot], 0, 0, 0);
      }
    }

    __syncthreads();             // xs tile reads done; reuse as out-assembly
    short* ob = &xs[0][0];       // 16384 shorts used

    if (mat == 0) {
#pragma unroll
      for (int ot = 0; ot < 4; ++ot)
#pragma unroll
        for (int nt = 0; nt < 4; ++nt) {
          int f = (nt * 16 + c16) * 256 + w * 64 + ot * 16 + g * 4;
          short4t s;
          s[0] = f2bf(acc[ot][nt][0] * INV_TEMP);
          s[1] = f2bf(acc[ot][nt][1] * INV_TEMP);
          s[2] = f2bf(acc[ot][nt][2] * INV_TEMP);
          s[3] = f2bf(acc[ot][nt][3] * INV_TEMP);
          *(short4t*)&ob[f] = s;
        }
    } else if (mat == 1) {
#pragma unroll
      for (int ot = 0; ot < 4; ++ot)
#pragma unroll
        for (int nt = 0; nt < 4; ++nt) {
          int koo = w * 2 + (ot >> 1);
          int pos = (((ot & 1) * 2 + (g >> 1)) ^ ((c16 >> 1) & 3));
          int f = nt * 4096 + koo * 512 + c16 * 32 + pos * 8 + (g & 1) * 4;
          short4t s;
          s[0] = f2bf(acc[ot][nt][0]);
          s[1] = f2bf(acc[ot][nt][1]);
          s[2] = f2bf(acc[ot][nt][2]);
          s[3] = f2bf(acc[ot][nt][3]);
          *(short4t*)&ob[f] = s;
        }
    } else {  // V: acc[mt][ot], rows m = mt*16+g*4+r, cols o = w*64+ot*16+c16
#pragma unroll
      for (int mt = 0; mt < 4; ++mt)
#pragma unroll
        for (int ot = 0; ot < 4; ++ot) {
          int o = w * 64 + ot * 16 + c16;
          int pos = (mt * 2 + (g >> 1)) ^ (o & 7);
          int f = o * 64 + pos * 8 + (g & 1) * 4;
          short4t s;
          s[0] = f2bf(acc[mt][ot][0]);
          s[1] = f2bf(acc[mt][ot][1]);
          s[2] = f2bf(acc[mt][ot][2]);
          s[3] = f2bf(acc[mt][ot][3]);
          *(short4t*)&ob[f] = s;
        }
    }
    __syncthreads();

    const uint4* s4 = (const uint4*)ob;
    uint4* d4 = (uint4*)dst;
#pragma unroll
    for (int j = 0; j < 8; ++j) d4[j * 256 + tid] = s4[j * 256 + tid];

    __syncthreads();             // xs reuse guard for next rep
    asm volatile("" ::: "memory");  // defeat cross-rep CSE/DSE
  }
}

// ---------------------------------------------------------------------------
// Flash attention v11 (unchanged). Grid (16, 32). Block 512 (8 waves).
// 2 WGs/CU. b = x&3; n0 = ((x>>2)*32 + y)*32.
// Waves 0-3 producers (16-key granules, 32 q-rows), 4-7 consumers (64-o).
// Separate role loops with matching barrier counts (66 each) -> register
// overlay. K/V direct global->reg, prefetched one interval ahead.
// LDS: ps 2x(32x72) + lsum = 9.75KB.
// ---------------------------------------------------------------------------
__global__ __launch_bounds__(512, 4) void flash_attn(
    const short* __restrict__ qg, const short* __restrict__ kt,
    const short* __restrict__ vt, float* __restrict__ out) {
  const int xg = blockIdx.x;                       // 0..15
  const int b  = xg & 3;
  const int n0 = (((xg >> 2) << 5) + blockIdx.y) * 32;   // 0..4064 step 32
  const int tid = threadIdx.x;
  const int w = tid >> 6, lane = tid & 63;
  const int g = lane >> 4, c16 = lane & 15;
  const int pw = w & 3;            // producer granule / consumer o-slice

  __shared__ short ps[2][32][72];  // P dbuf: 32 n x 64 m
  __shared__ float lsum[4][32];

  const short* ktb = kt + (size_t)b * N_ * O_;
  const short* vtb = vt + (size_t)b * N_ * O_;

  if (w < 4) {
    // ================= producer: S^T granule pw, exp, ps =================
    bf16x8 qf[2][8];                 // 32 q-rows x 256 o  (64 VGPRs)
    bf16x8 kf[8];                    // K(i) granule        (32 VGPRs)
    float lrun[2] = {0.f, 0.f};
    const int koff = c16 * 32 + ((g ^ ((c16 >> 1) & 3)) * 8);

#pragma unroll
    for (int nt = 0; nt < 2; ++nt) {
      const short* qrow =
          qg + (size_t)(b * N_ + n0 + nt * 16 + c16) * O_ + g * 8;
#pragma unroll
      for (int ko = 0; ko < 8; ++ko)
        qf[nt][ko] = *(const bf16x8*)(qrow + ko * 32);
    }
    {  // K(0)
      const short* kg = ktb + (size_t)pw * 4096;
#pragma unroll
      for (int j = 0; j < 8; ++j)
        kf[j] = *(const bf16x8*)(kg + j * 512 + koff);
    }

    for (int i = 0; i <= NIT; ++i) {
      if (i < NIT) {
        f32x4 sacc[2];
#pragma unroll
        for (int nt = 0; nt < 2; ++nt) sacc[nt] = (f32x4){0.f, 0.f, 0.f, 0.f};
        __builtin_amdgcn_s_setprio(1);
#pragma unroll
        for (int ko = 0; ko < 8; ++ko) {
#pragma unroll
          for (int nt = 0; nt < 2; ++nt)
            sacc[nt] = __builtin_amdgcn_mfma_f32_16x16x32_bf16(
                kf[ko], qf[nt][ko], sacc[nt], 0, 0, 0);
        }
        __builtin_amdgcn_s_setprio(0);
        if (i + 1 < NIT) {  // prefetch K(i+1); lands during next interval
          const short* kg = ktb + (size_t)(4 * (i + 1) + pw) * 4096;
#pragma unroll
          for (int j = 0; j < 8; ++j)
            kf[j] = *(const bf16x8*)(kg + j * 512 + koff);
        }
        // p = exp(s) (no max subtraction: |s| <= ~2.5 by construction)
#pragma unroll
        for (int nt = 0; nt < 2; ++nt) {
          short4t pb;
          float rs = 0.f;
#pragma unroll
          for (int r = 0; r < 4; ++r) {
            float p = __expf(sacc[nt][r]);
            rs += p;
            pb[r] = f2bf(p);
          }
          lrun[nt] += rs;
          *(short4t*)&ps[i & 1][nt * 16 + c16][pw * 16 + g * 4] = pb;
        }
      }
      asm volatile("s_waitcnt lgkmcnt(0)" ::: "memory");
      __builtin_amdgcn_s_barrier();
    }
    // publish granule row-sums
#pragma unroll
    for (int nt = 0; nt < 2; ++nt) {
      float v = lrun[nt];
      v += __shfl_xor(v, 16);
      v += __shfl_xor(v, 32);
      if (lane < 16) lsum[pw][nt * 16 + lane] = v;
    }
    asm volatile("s_waitcnt lgkmcnt(0)" ::: "memory");
    __builtin_amdgcn_s_barrier();                  // barrier #66
  } else {
    // ================= consumer: PV o-slice pw, normalize, store ==========
    bf16x8 vf[8];                    // V(i) slice          (32 VGPRs)
    f32x4 oacc[4][2];                // 64 o x 32 n         (32 VGPRs)
#pragma unroll
    for (int i = 0; i < 4; ++i)
#pragma unroll
      for (int j = 0; j < 2; ++j) oacc[i][j] = (f32x4){0.f, 0.f, 0.f, 0.f};

    for (int i = 0; i <= NIT; ++i) {
      if (i > 0) {  // O += V(i-1) P(i-1)^T  (vf holds V(i-1))
        const int pb_ = (i - 1) & 1;
        __builtin_amdgcn_s_setprio(1);
#pragma unroll
        for (int kk = 0; kk < 2; ++kk) {
          bf16x8 pf[2];
#pragma unroll
          for (int nt = 0; nt < 2; ++nt)
            pf[nt] = *(const bf16x8*)&ps[pb_][nt * 16 + c16][kk * 32 + g * 8];
#pragma unroll
          for (int ot = 0; ot < 4; ++ot) {
#pragma unroll
            for (int nt = 0; nt < 2; ++nt)
              oacc[ot][nt] = __builtin_amdgcn_mfma_f32_16x16x32_bf16(
                  vf[kk * 4 + ot], pf[nt], oacc[ot][nt], 0, 0, 0);
          }
        }
        __builtin_amdgcn_s_setprio(0);
      }
      if (i < NIT) {  // prefetch V(i) for use at interval i+1
        const short* vg = vtb + (size_t)i * 16384;
#pragma unroll
        for (int kk = 0; kk < 2; ++kk)
#pragma unroll
          for (int ot = 0; ot < 4; ++ot)
            vf[kk * 4 + ot] = *(const bf16x8*)(
                vg + (pw * 64 + ot * 16 + c16) * 64 +
                ((kk * 4 + g) ^ (c16 & 7)) * 8);
      }
      asm volatile("s_waitcnt lgkmcnt(0)" ::: "memory");
      __builtin_amdgcn_s_barrier();
    }
    __builtin_amdgcn_s_barrier();                  // barrier #66 (lsum ready)

#pragma unroll
    for (int nt = 0; nt < 2; ++nt) {
      const int nl = nt * 16 + c16;
      float l = lsum[0][nl] + lsum[1][nl] + lsum[2][nl] + lsum[3][nl];
      float li = 1.0f / l;
#pragma unroll
      for (int ot = 0; ot < 4; ++ot) {
        float* op = out + ((size_t)b * O_ + pw * 64 + ot * 16 + g * 4) * N_ +
                    n0 + nl;
#pragma unroll
        for (int r = 0; r < 4; ++r)
          op[(size_t)r * N_] = oacc[ot][nt][r] * li;
      }
    }
  }
}

// ---------------------------------------------------------------------------
extern "C" void kernel_launch(void* const* d_in, const int* in_sizes, int n_in,
                              void* d_out, int out_size, void* d_ws,
                              size_t ws_size, hipStream_t stream) {
  const float* x  = (const float*)d_in[0];
  const float* xx = (const float*)d_in[1];
  const float* Wq = (const float*)d_in[2];
  const float* Wk = (const float*)d_in[3];
  const float* Wv = (const float*)d_in[4];
  float* out = (float*)d_out;

  short* qg = (short*)d_ws;                         // 8.39 MB
  short* kt = qg + (size_t)B_ * N_ * O_;            // 8.39 MB (tiled K)
  short* vt = kt + (size_t)B_ * N_ * O_;            // 8.39 MB (tiled V)
  short* wb = vt + (size_t)B_ * N_ * O_;            // 384 KB

  wcvt<<<768, 256, 0, stream>>>(Wq, Wk, Wv, wb);
  qkv_proj<<<dim3(N_ / 64, B_, 3), 256, 0, stream>>>(x, xx, wb, qg, kt, vt);
  flash_attn<<<dim3(16, 32), 512, 0, stream>>>(qg, kt, vt, out);
}

// Round 8
// 201.028 us; speedup vs baseline: 1.8190x; 1.8190x over previous
//
#include <hip/hip_runtime.h>
#include <hip/hip_bf16.h>

// CrossAttention: B=4, C=256, N=4096, OUT=256, temp=16.
// v16: 3 dispatches -> 2. v15's cooperative mega-kernel failed correctness
//      (absmax 8.5e-2): cross-XCD visibility of plain stores through
//      grid.sync() is not trustworthy on MI355X (per-XCD L2s non-coherent,
//      Guideline 16). Keep the fusion gain with guaranteed semantics:
//      kernel boundary = the only cross-block sync.
//  - wcvt deleted; qkv_proj converts W f32->bf16 inline (same f2bf, bit-
//    identical numerics; W is L2-resident, ~2-3% VALU cost on proj).
//  - proj body otherwise v12 verbatim; flash v11 verbatim (99.5us control).
//  - v14 budget: flash 99.5 + proj ~46 + wcvt ~3 + gaps ~38. Removing one
//    dispatch + wcvt should cut ~16us.
// Workspace: qg 8.4MB + kt 8.4MB + vt 8.4MB (wb no longer used).

typedef __attribute__((ext_vector_type(8))) short bf16x8;
typedef __attribute__((ext_vector_type(4))) float f32x4;
typedef __attribute__((ext_vector_type(4))) short short4t;

constexpr int B_ = 4;
constexpr int C_ = 256;
constexpr int N_ = 4096;
constexpr int O_ = 256;
constexpr float INV_TEMP = 1.0f / 16.0f;
constexpr int NIT = 64;   // 64-key blocks (all 4096 keys, SPLIT=1)

__device__ __forceinline__ short f2bf(float f) {
  union { float f; unsigned u; } v; v.f = f;
  unsigned r = v.u + 0x7fffu + ((v.u >> 16) & 1u);   // RNE
  return (short)(r >> 16);
}

// ---------------------------------------------------------------------------
// Projections. Grid (64, B, 3). Block 256 (4 waves). z: 0=Q, 1=K, 2=V.
// v12 structure; W fragments loaded from f32 weights + inline f2bf.
// ---------------------------------------------------------------------------
__global__ __launch_bounds__(256, 2) void qkv_proj(
    const float* __restrict__ x, const float* __restrict__ xx,
    const float* __restrict__ Wq, const float* __restrict__ Wk,
    const float* __restrict__ Wv,
    short* __restrict__ qg, short* __restrict__ kt, short* __restrict__ vt) {
  const int n0  = blockIdx.x * 64;
  const int b   = blockIdx.y;
  const int mat = blockIdx.z;
  const float* src = (mat == 0) ? x : xx;
  const float* W   = (mat == 0) ? Wq : (mat == 1 ? Wk : Wv);
  const int tid = threadIdx.x;
  const int w = tid >> 6, lane = tid & 63;
  const int g = lane >> 4, c16 = lane & 15;

  __shared__ __align__(16) short xs[64][264];   // staged tile / out assembly

  {  // transpose staging, MLP-deep: all 64 strided loads, then write.
    const int n = tid & 63, cq = tid >> 6;
    const float* sp = src + (size_t)b * C_ * N_ + n0 + n;
    float xr[64];                                // stays in VGPRs (static idx)
#pragma unroll
    for (int rep = 0; rep < 16; ++rep)
#pragma unroll
      for (int j = 0; j < 4; ++j)
        xr[rep * 4 + j] = sp[(size_t)(rep * 16 + cq * 4 + j) * N_];
#pragma unroll
    for (int rep = 0; rep < 16; ++rep) {
      int c = rep * 16 + cq * 4;
      short4t s4;
#pragma unroll
      for (int j = 0; j < 4; ++j) s4[j] = f2bf(xr[rep * 4 + j]);
      *(short4t*)&xs[n][c] = s4;
    }
  }
  __syncthreads();

  f32x4 acc[4][4];
#pragma unroll
  for (int i = 0; i < 4; ++i)
#pragma unroll
    for (int j = 0; j < 4; ++j) acc[i][j] = (f32x4){0.f, 0.f, 0.f, 0.f};

#pragma unroll
  for (int ko = 0; ko < 8; ++ko) {
    bf16x8 wfr[4], xfr[4];
#pragma unroll
    for (int ot = 0; ot < 4; ++ot) {
      const float* wrow = W + (size_t)(w * 64 + ot * 16 + c16) * C_ +
                          ko * 32 + g * 8;
      f32x4 w0 = *(const f32x4*)(wrow);
      f32x4 w1 = *(const f32x4*)(wrow + 4);
      bf16x8 wv;
#pragma unroll
      for (int j = 0; j < 4; ++j) wv[j] = f2bf(w0[j]);
#pragma unroll
      for (int j = 0; j < 4; ++j) wv[4 + j] = f2bf(w1[j]);
      wfr[ot] = wv;
    }
#pragma unroll
    for (int nt = 0; nt < 4; ++nt)
      xfr[nt] = *(const bf16x8*)&xs[nt * 16 + c16][ko * 32 + g * 8];
    if (mat < 2) {
#pragma unroll
      for (int ot = 0; ot < 4; ++ot)
#pragma unroll
        for (int nt = 0; nt < 4; ++nt)
          acc[ot][nt] = __builtin_amdgcn_mfma_f32_16x16x32_bf16(
              wfr[ot], xfr[nt], acc[ot][nt], 0, 0, 0);
    } else {  // V: swapped operands -> D rows = m, cols = o
#pragma unroll
      for (int mt = 0; mt < 4; ++mt)
#pragma unroll
        for (int ot = 0; ot < 4; ++ot)
          acc[mt][ot] = __builtin_amdgcn_mfma_f32_16x16x32_bf16(
              xfr[mt], wfr[ot], acc[mt][ot], 0, 0, 0);
    }
  }

  __syncthreads();               // xs tile reads done; reuse as out-assembly
  short* ob = &xs[0][0];         // 16384 shorts used

  if (mat == 0) {
#pragma unroll
    for (int ot = 0; ot < 4; ++ot)
#pragma unroll
      for (int nt = 0; nt < 4; ++nt) {
        int f = (nt * 16 + c16) * 256 + w * 64 + ot * 16 + g * 4;
        short4t s;
        s[0] = f2bf(acc[ot][nt][0] * INV_TEMP);
        s[1] = f2bf(acc[ot][nt][1] * INV_TEMP);
        s[2] = f2bf(acc[ot][nt][2] * INV_TEMP);
        s[3] = f2bf(acc[ot][nt][3] * INV_TEMP);
        *(short4t*)&ob[f] = s;
      }
  } else if (mat == 1) {
#pragma unroll
    for (int ot = 0; ot < 4; ++ot)
#pragma unroll
      for (int nt = 0; nt < 4; ++nt) {
        int koo = w * 2 + (ot >> 1);
        int pos = (((ot & 1) * 2 + (g >> 1)) ^ ((c16 >> 1) & 3));
        int f = nt * 4096 + koo * 512 + c16 * 32 + pos * 8 + (g & 1) * 4;
        short4t s;
        s[0] = f2bf(acc[ot][nt][0]);
        s[1] = f2bf(acc[ot][nt][1]);
        s[2] = f2bf(acc[ot][nt][2]);
        s[3] = f2bf(acc[ot][nt][3]);
        *(short4t*)&ob[f] = s;
      }
  } else {  // V: acc[mt][ot], rows m = mt*16+g*4+r, cols o = w*64+ot*16+c16
#pragma unroll
    for (int mt = 0; mt < 4; ++mt)
#pragma unroll
      for (int ot = 0; ot < 4; ++ot) {
        int o = w * 64 + ot * 16 + c16;
        int pos = (mt * 2 + (g >> 1)) ^ (o & 7);
        int f = o * 64 + pos * 8 + (g & 1) * 4;
        short4t s;
        s[0] = f2bf(acc[mt][ot][0]);
        s[1] = f2bf(acc[mt][ot][1]);
        s[2] = f2bf(acc[mt][ot][2]);
        s[3] = f2bf(acc[mt][ot][3]);
        *(short4t*)&ob[f] = s;
      }
  }
  __syncthreads();

  short* dst = (mat == 0) ? qg + ((size_t)b * N_ + n0) * O_
             : (mat == 1) ? kt + (size_t)(b * 256 + (n0 >> 4)) * 4096
                          : vt + (size_t)(b * 64 + (n0 >> 6)) * 16384;
  const uint4* s4 = (const uint4*)ob;
  uint4* d4 = (uint4*)dst;
#pragma unroll
  for (int j = 0; j < 8; ++j) d4[j * 256 + tid] = s4[j * 256 + tid];
}

// ---------------------------------------------------------------------------
// Flash attention v11 (unchanged). Grid (16, 32). Block 512 (8 waves).
// 2 WGs/CU. b = x&3; n0 = ((x>>2)*32 + y)*32.
// Waves 0-3 producers (16-key granules, 32 q-rows), 4-7 consumers (64-o).
// Separate role loops with matching barrier counts (66 each) -> register
// overlay. K/V direct global->reg, prefetched one interval ahead.
// LDS: ps 2x(32x72) + lsum = 9.75KB.
// ---------------------------------------------------------------------------
__global__ __launch_bounds__(512, 4) void flash_attn(
    const short* __restrict__ qg, const short* __restrict__ kt,
    const short* __restrict__ vt, float* __restrict__ out) {
  const int xg = blockIdx.x;                       // 0..15
  const int b  = xg & 3;
  const int n0 = (((xg >> 2) << 5) + blockIdx.y) * 32;   // 0..4064 step 32
  const int tid = threadIdx.x;
  const int w = tid >> 6, lane = tid & 63;
  const int g = lane >> 4, c16 = lane & 15;
  const int pw = w & 3;            // producer granule / consumer o-slice

  __shared__ short ps[2][32][72];  // P dbuf: 32 n x 64 m
  __shared__ float lsum[4][32];

  const short* ktb = kt + (size_t)b * N_ * O_;
  const short* vtb = vt + (size_t)b * N_ * O_;

  if (w < 4) {
    // ================= producer: S^T granule pw, exp, ps =================
    bf16x8 qf[2][8];                 // 32 q-rows x 256 o  (64 VGPRs)
    bf16x8 kf[8];                    // K(i) granule        (32 VGPRs)
    float lrun[2] = {0.f, 0.f};
    const int koff = c16 * 32 + ((g ^ ((c16 >> 1) & 3)) * 8);

#pragma unroll
    for (int nt = 0; nt < 2; ++nt) {
      const short* qrow =
          qg + (size_t)(b * N_ + n0 + nt * 16 + c16) * O_ + g * 8;
#pragma unroll
      for (int ko = 0; ko < 8; ++ko)
        qf[nt][ko] = *(const bf16x8*)(qrow + ko * 32);
    }
    {  // K(0)
      const short* kg = ktb + (size_t)pw * 4096;
#pragma unroll
      for (int j = 0; j < 8; ++j)
        kf[j] = *(const bf16x8*)(kg + j * 512 + koff);
    }

    for (int i = 0; i <= NIT; ++i) {
      if (i < NIT) {
        f32x4 sacc[2];
#pragma unroll
        for (int nt = 0; nt < 2; ++nt) sacc[nt] = (f32x4){0.f, 0.f, 0.f, 0.f};
        __builtin_amdgcn_s_setprio(1);
#pragma unroll
        for (int ko = 0; ko < 8; ++ko) {
#pragma unroll
          for (int nt = 0; nt < 2; ++nt)
            sacc[nt] = __builtin_amdgcn_mfma_f32_16x16x32_bf16(
                kf[ko], qf[nt][ko], sacc[nt], 0, 0, 0);
        }
        __builtin_amdgcn_s_setprio(0);
        if (i + 1 < NIT) {  // prefetch K(i+1); lands during next interval
          const short* kg = ktb + (size_t)(4 * (i + 1) + pw) * 4096;
#pragma unroll
          for (int j = 0; j < 8; ++j)
            kf[j] = *(const bf16x8*)(kg + j * 512 + koff);
        }
        // p = exp(s) (no max subtraction: |s| <= ~2.5 by construction)
#pragma unroll
        for (int nt = 0; nt < 2; ++nt) {
          short4t pb;
          float rs = 0.f;
#pragma unroll
          for (int r = 0; r < 4; ++r) {
            float p = __expf(sacc[nt][r]);
            rs += p;
            pb[r] = f2bf(p);
          }
          lrun[nt] += rs;
          *(short4t*)&ps[i & 1][nt * 16 + c16][pw * 16 + g * 4] = pb;
        }
      }
      asm volatile("s_waitcnt lgkmcnt(0)" ::: "memory");
      __builtin_amdgcn_s_barrier();
    }
    // publish granule row-sums
#pragma unroll
    for (int nt = 0; nt < 2; ++nt) {
      float v = lrun[nt];
      v += __shfl_xor(v, 16);
      v += __shfl_xor(v, 32);
      if (lane < 16) lsum[pw][nt * 16 + lane] = v;
    }
    asm volatile("s_waitcnt lgkmcnt(0)" ::: "memory");
    __builtin_amdgcn_s_barrier();                  // barrier #66
  } else {
    // ================= consumer: PV o-slice pw, normalize, store ==========
    bf16x8 vf[8];                    // V(i) slice          (32 VGPRs)
    f32x4 oacc[4][2];                // 64 o x 32 n         (32 VGPRs)
#pragma unroll
    for (int i = 0; i < 4; ++i)
#pragma unroll
      for (int j = 0; j < 2; ++j) oacc[i][j] = (f32x4){0.f, 0.f, 0.f, 0.f};

    for (int i = 0; i <= NIT; ++i) {
      if (i > 0) {  // O += V(i-1) P(i-1)^T  (vf holds V(i-1))
        const int pb_ = (i - 1) & 1;
        __builtin_amdgcn_s_setprio(1);
#pragma unroll
        for (int kk = 0; kk < 2; ++kk) {
          bf16x8 pf[2];
#pragma unroll
          for (int nt = 0; nt < 2; ++nt)
            pf[nt] = *(const bf16x8*)&ps[pb_][nt * 16 + c16][kk * 32 + g * 8];
#pragma unroll
          for (int ot = 0; ot < 4; ++ot) {
#pragma unroll
            for (int nt = 0; nt < 2; ++nt)
              oacc[ot][nt] = __builtin_amdgcn_mfma_f32_16x16x32_bf16(
                  vf[kk * 4 + ot], pf[nt], oacc[ot][nt], 0, 0, 0);
          }
        }
        __builtin_amdgcn_s_setprio(0);
      }
      if (i < NIT) {  // prefetch V(i) for use at interval i+1
        const short* vg = vtb + (size_t)i * 16384;
#pragma unroll
        for (int kk = 0; kk < 2; ++kk)
#pragma unroll
          for (int ot = 0; ot < 4; ++ot)
            vf[kk * 4 + ot] = *(const bf16x8*)(
                vg + (pw * 64 + ot * 16 + c16) * 64 +
                ((kk * 4 + g) ^ (c16 & 7)) * 8);
      }
      asm volatile("s_waitcnt lgkmcnt(0)" ::: "memory");
      __builtin_amdgcn_s_barrier();
    }
    __builtin_amdgcn_s_barrier();                  // barrier #66 (lsum ready)

#pragma unroll
    for (int nt = 0; nt < 2; ++nt) {
      const int nl = nt * 16 + c16;
      float l = lsum[0][nl] + lsum[1][nl] + lsum[2][nl] + lsum[3][nl];
      float li = 1.0f / l;
#pragma unroll
      for (int ot = 0; ot < 4; ++ot) {
        float* op = out + ((size_t)b * O_ + pw * 64 + ot * 16 + g * 4) * N_ +
                    n0 + nl;
#pragma unroll
        for (int r = 0; r < 4; ++r)
          op[(size_t)r * N_] = oacc[ot][nt][r] * li;
      }
    }
  }
}

// ---------------------------------------------------------------------------
extern "C" void kernel_launch(void* const* d_in, const int* in_sizes, int n_in,
                              void* d_out, int out_size, void* d_ws,
                              size_t ws_size, hipStream_t stream) {
  const float* x  = (const float*)d_in[0];
  const float* xx = (const float*)d_in[1];
  const float* Wq = (const float*)d_in[2];
  const float* Wk = (const float*)d_in[3];
  const float* Wv = (const float*)d_in[4];
  float* out = (float*)d_out;

  short* qg = (short*)d_ws;                         // 8.39 MB
  short* kt = qg + (size_t)B_ * N_ * O_;            // 8.39 MB (tiled K)
  short* vt = kt + (size_t)B_ * N_ * O_;            // 8.39 MB (tiled V)

  qkv_proj<<<dim3(N_ / 64, B_, 3), 256, 0, stream>>>(x, xx, Wq, Wk, Wv,
                                                     qg, kt, vt);
  flash_attn<<<dim3(16, 32), 512, 0, stream>>>(qg, kt, vt, out);
}

// Round 9
// 193.817 us; speedup vs baseline: 1.8866x; 1.0372x over previous
//
#include <hip/hip_runtime.h>
#include <hip/hip_bf16.h>

// CrossAttention: B=4, C=256, N=4096, OUT=256, temp=16.
// v17: flash barrier-every-2-intervals. proj/wcvt reverted to v12 verbatim
//      (v16's inline W-conversion cost +30us vs -16us saved; v12=187.0 best).
//  - flash: ps deepened to 4 buffers (19KB LDS), consumer lags 2 intervals
//    (PV(i-2) at interval i; V(i-1) loaded at interval i, single vf set),
//    raw s_barrier only after ODD intervals -> 33+1 barriers vs 66.
//    Race audit: between consecutive barriers producer writes ps buffers
//    {(2m+2)&3,(2m+3)&3}, consumer reads {2m&3,(2m+1)&3} - disjoint mod 4;
//    RAW(write j -> read j+2) and WAR(read j+2 -> write j+4) each bracket
//    a barrier. Producer 32+1+1 = consumer 33+1 barrier counts match.
//  - Theory: 65 per-interval barriers lockstep 8 waves to max(P,C) each
//    interval (~1700 cyc/interval unexplained stall); halving barrier
//    frequency lets roles drift +-1 interval and absorb imbalance.
// Workspace: qg 8.4MB + kt 8.4MB + vt 8.4MB + wb 384KB.

typedef __attribute__((ext_vector_type(8))) short bf16x8;
typedef __attribute__((ext_vector_type(4))) float f32x4;
typedef __attribute__((ext_vector_type(4))) short short4t;

constexpr int B_ = 4;
constexpr int C_ = 256;
constexpr int N_ = 4096;
constexpr int O_ = 256;
constexpr float INV_TEMP = 1.0f / 16.0f;
constexpr int NIT = 64;   // 64-key blocks (all 4096 keys, SPLIT=1)

__device__ __forceinline__ short f2bf(float f) {
  union { float f; unsigned u; } v; v.f = f;
  unsigned r = v.u + 0x7fffu + ((v.u >> 16) & 1u);   // RNE
  return (short)(r >> 16);
}

// ---------------------------------------------------------------------------
__global__ void wcvt(const float* __restrict__ Wq, const float* __restrict__ Wk,
                     const float* __restrict__ Wv, short* __restrict__ wb) {
  int i = blockIdx.x * 256 + threadIdx.x;        // 0..196607
  int mat = i >> 16, off = i & 65535;
  const float* W = (mat == 0) ? Wq : (mat == 1 ? Wk : Wv);
  wb[i] = f2bf(W[off]);
}

// ---------------------------------------------------------------------------
// Projections (v12 verbatim). Grid (64, B, 3). Block 256 (4 waves).
// ---------------------------------------------------------------------------
__global__ __launch_bounds__(256, 2) void qkv_proj(
    const float* __restrict__ x, const float* __restrict__ xx,
    const short* __restrict__ wb,
    short* __restrict__ qg, short* __restrict__ kt, short* __restrict__ vt) {
  const int n0  = blockIdx.x * 64;
  const int b   = blockIdx.y;
  const int mat = blockIdx.z;
  const float* src = (mat == 0) ? x : xx;
  const short* W   = wb + mat * 65536;
  const int tid = threadIdx.x;
  const int w = tid >> 6, lane = tid & 63;
  const int g = lane >> 4, c16 = lane & 15;

  __shared__ __align__(16) short xs[64][264];   // staged tile / out assembly

  {  // transpose staging, MLP-deep: all 64 strided loads, then write.
    const int n = tid & 63, cq = tid >> 6;
    const float* sp = src + (size_t)b * C_ * N_ + n0 + n;
    float xr[64];                                // stays in VGPRs (static idx)
#pragma unroll
    for (int rep = 0; rep < 16; ++rep)
#pragma unroll
      for (int j = 0; j < 4; ++j)
        xr[rep * 4 + j] = sp[(size_t)(rep * 16 + cq * 4 + j) * N_];
#pragma unroll
    for (int rep = 0; rep < 16; ++rep) {
      int c = rep * 16 + cq * 4;
      short4t s4;
#pragma unroll
      for (int j = 0; j < 4; ++j) s4[j] = f2bf(xr[rep * 4 + j]);
      *(short4t*)&xs[n][c] = s4;
    }
  }
  __syncthreads();

  f32x4 acc[4][4];
#pragma unroll
  for (int i = 0; i < 4; ++i)
#pragma unroll
    for (int j = 0; j < 4; ++j) acc[i][j] = (f32x4){0.f, 0.f, 0.f, 0.f};

#pragma unroll
  for (int ko = 0; ko < 8; ++ko) {
    bf16x8 wfr[4], xfr[4];
#pragma unroll
    for (int ot = 0; ot < 4; ++ot)
      wfr[ot] = *(const bf16x8*)&W[(w * 64 + ot * 16 + c16) * C_ + ko * 32 + g * 8];
#pragma unroll
    for (int nt = 0; nt < 4; ++nt)
      xfr[nt] = *(const bf16x8*)&xs[nt * 16 + c16][ko * 32 + g * 8];
    if (mat < 2) {
#pragma unroll
      for (int ot = 0; ot < 4; ++ot)
#pragma unroll
        for (int nt = 0; nt < 4; ++nt)
          acc[ot][nt] = __builtin_amdgcn_mfma_f32_16x16x32_bf16(
              wfr[ot], xfr[nt], acc[ot][nt], 0, 0, 0);
    } else {  // V: swapped operands -> D rows = m, cols = o
#pragma unroll
      for (int mt = 0; mt < 4; ++mt)
#pragma unroll
        for (int ot = 0; ot < 4; ++ot)
          acc[mt][ot] = __builtin_amdgcn_mfma_f32_16x16x32_bf16(
              xfr[mt], wfr[ot], acc[mt][ot], 0, 0, 0);
    }
  }

  __syncthreads();               // xs tile reads done; reuse as out-assembly
  short* ob = &xs[0][0];         // 16384 shorts used

  if (mat == 0) {
#pragma unroll
    for (int ot = 0; ot < 4; ++ot)
#pragma unroll
      for (int nt = 0; nt < 4; ++nt) {
        int f = (nt * 16 + c16) * 256 + w * 64 + ot * 16 + g * 4;
        short4t s;
        s[0] = f2bf(acc[ot][nt][0] * INV_TEMP);
        s[1] = f2bf(acc[ot][nt][1] * INV_TEMP);
        s[2] = f2bf(acc[ot][nt][2] * INV_TEMP);
        s[3] = f2bf(acc[ot][nt][3] * INV_TEMP);
        *(short4t*)&ob[f] = s;
      }
  } else if (mat == 1) {
#pragma unroll
    for (int ot = 0; ot < 4; ++ot)
#pragma unroll
      for (int nt = 0; nt < 4; ++nt) {
        int koo = w * 2 + (ot >> 1);
        int pos = (((ot & 1) * 2 + (g >> 1)) ^ ((c16 >> 1) & 3));
        int f = nt * 4096 + koo * 512 + c16 * 32 + pos * 8 + (g & 1) * 4;
        short4t s;
        s[0] = f2bf(acc[ot][nt][0]);
        s[1] = f2bf(acc[ot][nt][1]);
        s[2] = f2bf(acc[ot][nt][2]);
        s[3] = f2bf(acc[ot][nt][3]);
        *(short4t*)&ob[f] = s;
      }
  } else {  // V: acc[mt][ot], rows m = mt*16+g*4+r, cols o = w*64+ot*16+c16
#pragma unroll
    for (int mt = 0; mt < 4; ++mt)
#pragma unroll
      for (int ot = 0; ot < 4; ++ot) {
        int o = w * 64 + ot * 16 + c16;
        int pos = (mt * 2 + (g >> 1)) ^ (o & 7);
        int f = o * 64 + pos * 8 + (g & 1) * 4;
        short4t s;
        s[0] = f2bf(acc[mt][ot][0]);
        s[1] = f2bf(acc[mt][ot][1]);
        s[2] = f2bf(acc[mt][ot][2]);
        s[3] = f2bf(acc[mt][ot][3]);
        *(short4t*)&ob[f] = s;
      }
  }
  __syncthreads();

  short* dst = (mat == 0) ? qg + ((size_t)b * N_ + n0) * O_
             : (mat == 1) ? kt + (size_t)(b * 256 + (n0 >> 4)) * 4096
                          : vt + (size_t)(b * 64 + (n0 >> 6)) * 16384;
  const uint4* s4 = (const uint4*)ob;
  uint4* d4 = (uint4*)dst;
#pragma unroll
  for (int j = 0; j < 8; ++j) d4[j * 256 + tid] = s4[j * 256 + tid];
}

// ---------------------------------------------------------------------------
// Flash attention v17. Grid (16, 32). Block 512 (8 waves). 2 WGs/CU.
// b = x&3; n0 = ((x>>2)*32 + y)*32.
// Waves 0-3 producers (16-key granules, 32 q-rows), 4-7 consumers (64-o).
// ps 4-deep; consumer lags 2 intervals; barrier after ODD intervals only.
// LDS: ps 4x(32x72) + lsum = 18.9KB.
// ---------------------------------------------------------------------------
__global__ __launch_bounds__(512, 4) void flash_attn(
    const short* __restrict__ qg, const short* __restrict__ kt,
    const short* __restrict__ vt, float* __restrict__ out) {
  const int xg = blockIdx.x;                       // 0..15
  const int b  = xg & 3;
  const int n0 = (((xg >> 2) << 5) + blockIdx.y) * 32;   // 0..4064 step 32
  const int tid = threadIdx.x;
  const int w = tid >> 6, lane = tid & 63;
  const int g = lane >> 4, c16 = lane & 15;
  const int pw = w & 3;            // producer granule / consumer o-slice

  __shared__ short ps[4][32][72];  // P 4-deep: 32 n x 64 m each
  __shared__ float lsum[4][32];

  const short* ktb = kt + (size_t)b * N_ * O_;
  const short* vtb = vt + (size_t)b * N_ * O_;

  if (w < 4) {
    // ================= producer: S^T granule pw, exp, ps =================
    bf16x8 qf[2][8];                 // 32 q-rows x 256 o  (64 VGPRs)
    bf16x8 kf[8];                    // K(i) granule        (32 VGPRs)
    float lrun[2] = {0.f, 0.f};
    const int koff = c16 * 32 + ((g ^ ((c16 >> 1) & 3)) * 8);

#pragma unroll
    for (int nt = 0; nt < 2; ++nt) {
      const short* qrow =
          qg + (size_t)(b * N_ + n0 + nt * 16 + c16) * O_ + g * 8;
#pragma unroll
      for (int ko = 0; ko < 8; ++ko)
        qf[nt][ko] = *(const bf16x8*)(qrow + ko * 32);
    }
    {  // K(0)
      const short* kg = ktb + (size_t)pw * 4096;
#pragma unroll
      for (int j = 0; j < 8; ++j)
        kf[j] = *(const bf16x8*)(kg + j * 512 + koff);
    }

    for (int i = 0; i < NIT; ++i) {            // intervals 0..63
      f32x4 sacc[2];
#pragma unroll
      for (int nt = 0; nt < 2; ++nt) sacc[nt] = (f32x4){0.f, 0.f, 0.f, 0.f};
      __builtin_amdgcn_s_setprio(1);
#pragma unroll
      for (int ko = 0; ko < 8; ++ko) {
#pragma unroll
        for (int nt = 0; nt < 2; ++nt)
          sacc[nt] = __builtin_amdgcn_mfma_f32_16x16x32_bf16(
              kf[ko], qf[nt][ko], sacc[nt], 0, 0, 0);
      }
      __builtin_amdgcn_s_setprio(0);
      if (i + 1 < NIT) {  // prefetch K(i+1); exp/ps-write covers latency
        const short* kg = ktb + (size_t)(4 * (i + 1) + pw) * 4096;
#pragma unroll
        for (int j = 0; j < 8; ++j)
          kf[j] = *(const bf16x8*)(kg + j * 512 + koff);
      }
      // p = exp(s) (no max subtraction: |s| <= ~2.5 by construction)
#pragma unroll
      for (int nt = 0; nt < 2; ++nt) {
        short4t pb;
        float rs = 0.f;
#pragma unroll
        for (int r = 0; r < 4; ++r) {
          float p = __expf(sacc[nt][r]);
          rs += p;
          pb[r] = f2bf(p);
        }
        lrun[nt] += rs;
        *(short4t*)&ps[i & 3][nt * 16 + c16][pw * 16 + g * 4] = pb;
      }
      if (i & 1) {                             // barriers at i=1,3,..,63: 32
        asm volatile("s_waitcnt lgkmcnt(0)" ::: "memory");
        __builtin_amdgcn_s_barrier();
      }
    }
    // tail barrier matching consumer's i=65 barrier (33rd)
    asm volatile("s_waitcnt lgkmcnt(0)" ::: "memory");
    __builtin_amdgcn_s_barrier();
    // publish granule row-sums
#pragma unroll
    for (int nt = 0; nt < 2; ++nt) {
      float v = lrun[nt];
      v += __shfl_xor(v, 16);
      v += __shfl_xor(v, 32);
      if (lane < 16) lsum[pw][nt * 16 + lane] = v;
    }
    asm volatile("s_waitcnt lgkmcnt(0)" ::: "memory");
    __builtin_amdgcn_s_barrier();              // 34th (lsum ready)
  } else {
    // ================= consumer: PV o-slice pw, normalize, store ==========
    bf16x8 vf[8];                    // V(j) slice          (32 VGPRs)
    f32x4 oacc[4][2];                // 64 o x 32 n         (32 VGPRs)
#pragma unroll
    for (int i = 0; i < 4; ++i)
#pragma unroll
      for (int j = 0; j < 2; ++j) oacc[i][j] = (f32x4){0.f, 0.f, 0.f, 0.f};

    for (int i = 0; i <= NIT + 1; ++i) {       // intervals 0..65
      if (i >= 2) {  // O += V(i-2) P(i-2)^T   (vf holds V(i-2))
        const int pb_ = (i - 2) & 3;
        __builtin_amdgcn_s_setprio(1);
#pragma unroll
        for (int kk = 0; kk < 2; ++kk) {
          bf16x8 pf[2];
#pragma unroll
          for (int nt = 0; nt < 2; ++nt)
            pf[nt] = *(const bf16x8*)&ps[pb_][nt * 16 + c16][kk * 32 + g * 8];
#pragma unroll
          for (int ot = 0; ot < 4; ++ot) {
#pragma unroll
            for (int nt = 0; nt < 2; ++nt)
              oacc[ot][nt] = __builtin_amdgcn_mfma_f32_16x16x32_bf16(
                  vf[kk * 4 + ot], pf[nt], oacc[ot][nt], 0, 0, 0);
          }
        }
        __builtin_amdgcn_s_setprio(0);
      }
      if (i >= 1 && i - 1 < NIT) {  // load V(i-1), used at interval i+1
        const short* vg = vtb + (size_t)(i - 1) * 16384;
#pragma unroll
        for (int kk = 0; kk < 2; ++kk)
#pragma unroll
          for (int ot = 0; ot < 4; ++ot)
            vf[kk * 4 + ot] = *(const bf16x8*)(
                vg + (pw * 64 + ot * 16 + c16) * 64 +
                ((kk * 4 + g) ^ (c16 & 7)) * 8);
      }
      if (i & 1) {                             // barriers at i=1,3,..,65: 33
        asm volatile("s_waitcnt lgkmcnt(0)" ::: "memory");
        __builtin_amdgcn_s_barrier();
      }
    }
    __builtin_amdgcn_s_barrier();              // 34th (lsum ready)

#pragma unroll
    for (int nt = 0; nt < 2; ++nt) {
      const int nl = nt * 16 + c16;
      float l = lsum[0][nl] + lsum[1][nl] + lsum[2][nl] + lsum[3][nl];
      float li = 1.0f / l;
#pragma unroll
      for (int ot = 0; ot < 4; ++ot) {
        float* op = out + ((size_t)b * O_ + pw * 64 + ot * 16 + g * 4) * N_ +
                    n0 + nl;
#pragma unroll
        for (int r = 0; r < 4; ++r)
          op[(size_t)r * N_] = oacc[ot][nt][r] * li;
      }
    }
  }
}

// ---------------------------------------------------------------------------
extern "C" void kernel_launch(void* const* d_in, const int* in_sizes, int n_in,
                              void* d_out, int out_size, void* d_ws,
                              size_t ws_size, hipStream_t stream) {
  const float* x  = (const float*)d_in[0];
  const float* xx = (const float*)d_in[1];
  const float* Wq = (const float*)d_in[2];
  const float* Wk = (const float*)d_in[3];
  const float* Wv = (const float*)d_in[4];
  float* out = (float*)d_out;

  short* qg = (short*)d_ws;                         // 8.39 MB
  short* kt = qg + (size_t)B_ * N_ * O_;            // 8.39 MB (tiled K)
  short* vt = kt + (size_t)B_ * N_ * O_;            // 8.39 MB (tiled V)
  short* wb = vt + (size_t)B_ * N_ * O_;            // 384 KB

  wcvt<<<768, 256, 0, stream>>>(Wq, Wk, Wv, wb);
  qkv_proj<<<dim3(N_ / 64, B_, 3), 256, 0, stream>>>(x, xx, wb, qg, kt, vt);
  flash_attn<<<dim3(16, 32), 512, 0, stream>>>(qg, kt, vt, out);
}